// Round 11
// baseline (220.115 us; speedup 1.0000x reference)
//
#include <hip/hip_runtime.h>
#include <hip/hip_bf16.h>
#include <math.h>

// Problem constants (B,S,D,H,WIN) = (2,2048,1024,16,128), DH=64
#define BB    2
#define SS    2048
#define DD    1024
#define HH    16
#define DHH   64
#define WINW  128
#define MROWS (BB * SS)          // 4096

typedef __attribute__((ext_vector_type(8))) short short8;
typedef __attribute__((ext_vector_type(4))) short short4v;
typedef __attribute__((ext_vector_type(4))) float floatx4;

__device__ __forceinline__ float bf2f(short s) {
  union { unsigned u; float f; } t;
  t.u = ((unsigned)(unsigned short)s) << 16;
  return t.f;
}

// ---------------------------------------------------------------------------
__device__ inline void load16_lds(const __hip_bfloat16* g, __hip_bfloat16* l) {
  __builtin_amdgcn_global_load_lds(
      (const __attribute__((address_space(1))) uint32_t*)g,
      (__attribute__((address_space(3))) uint32_t*)l, 16, 0, 0);
}

// ---------------------------------------------------------------------------
// Fused preprocessing (one launch, 2080 blocks ~= one scheduling generation):
//  [0,1024)    x fp32 -> xT_bf bf16 transposed + x_bf bf16 row-major
//  [1024,1536) weight casts fp32->bf16, 8192 elems/block
//  [1536,2080) wr/wi -> bf16 transposed [1024][1025]
// ---------------------------------------------------------------------------
__global__ __launch_bounds__(256) void prep_fused(
    const float* __restrict__ x, __hip_bfloat16* __restrict__ xT_bf,
    __hip_bfloat16* __restrict__ x_bf,
    const float* __restrict__ w_in, const float* __restrict__ w_out,
    __hip_bfloat16* __restrict__ w_in_bf, __hip_bfloat16* __restrict__ w_out_bf,
    const float* __restrict__ wr, const float* __restrict__ wi,
    __hip_bfloat16* __restrict__ wrT, __hip_bfloat16* __restrict__ wiT) {
  __shared__ float tile[64][65];
  const int id = blockIdx.x;
  const int tx = threadIdx.x & 63;
  const int ty = threadIdx.x >> 6;

  if (id < 1024) {
    const int bz = id >> 9;
    const int rem = id & 511;
    const int c0 = (rem & 15) * 64;   // D
    const int r0 = (rem >> 4) * 64;   // S
    const size_t base = (size_t)bz * SS * DD;
#pragma unroll
    for (int i = 0; i < 16; ++i) {
      const int r = ty * 16 + i;
      const float v = x[base + (size_t)(r0 + r) * DD + c0 + tx];
      tile[r][tx] = v;
      x_bf[base + (size_t)(r0 + r) * DD + c0 + tx] = __float2bfloat16(v);
    }
    __syncthreads();
#pragma unroll
    for (int i = 0; i < 16; ++i) {
      const int c = ty * 16 + i;
      xT_bf[base + (size_t)(c0 + c) * SS + r0 + tx] = __float2bfloat16(tile[tx][c]);
    }
  } else if (id < 1536) {
    const int blk = id - 1024;
    const float* src; __hip_bfloat16* dst; size_t off;
    if (blk < 384) { src = w_in; dst = w_in_bf; off = (size_t)blk * 8192; }
    else { src = w_out; dst = w_out_bf; off = (size_t)(blk - 384) * 8192; }
#pragma unroll
    for (int c = 0; c < 8; ++c) {
      const size_t j = off + c * 1024 + threadIdx.x * 4;
      const float4 v = *(const float4*)(src + j);
      dst[j + 0] = __float2bfloat16(v.x);
      dst[j + 1] = __float2bfloat16(v.y);
      dst[j + 2] = __float2bfloat16(v.z);
      dst[j + 3] = __float2bfloat16(v.w);
    }
  } else {
    const int id2 = id - 1536;               // 0..543
    const int half = id2 >= 272;
    const int rem = id2 - (half ? 272 : 0);
    const float* src = half ? wi : wr;
    __hip_bfloat16* dst = half ? wiT : wrT;
    const int R = 1025, C = DD;
    const int c0 = (rem & 15) * 64;
    const int r0 = (rem >> 4) * 64;
#pragma unroll
    for (int i = 0; i < 16; ++i) {
      const int r = ty * 16 + i;
      if (r0 + r < R) tile[r][tx] = src[(size_t)(r0 + r) * C + c0 + tx];
    }
    __syncthreads();
#pragma unroll
    for (int i = 0; i < 16; ++i) {
      const int c = ty * 16 + i;
      if (r0 + tx < R) dst[(size_t)(c0 + c) * R + r0 + tx] = __float2bfloat16(tile[tx][c]);
    }
  }
}

// ---------------------------------------------------------------------------
// bf16 MFMA GEMM tile body (BK=64, unchanged). sm: 32 KB.
// ---------------------------------------------------------------------------
template <bool BF16OUT>
__device__ __forceinline__ void gemm_tile128(
    const __hip_bfloat16* __restrict__ A, const __hip_bfloat16* __restrict__ B,
    const float* __restrict__ bias, void* __restrict__ Cp,
    int N, int K, int row0, int col0, __hip_bfloat16* sm) {
  __hip_bfloat16* As0 = sm;
  __hip_bfloat16* As1 = sm + 4096;
  __hip_bfloat16* Bs0 = sm + 8192;
  __hip_bfloat16* Bs1 = sm + 12288;
  const int tid  = threadIdx.x;
  const int lane = tid & 63;
  const int wave = tid >> 6;
  const int wrow = (wave >> 1) * 64;
  const int wcol = (wave & 1) * 64;
  const int srow = tid >> 2;
  const int skk  = (tid & 3) * 8;
  const int quad = lane >> 4;
  const int l16  = lane & 15;
  floatx4 acc[4][4] = {};
  for (int k0 = 0; k0 < K; k0 += 64) {
    __syncthreads();
    load16_lds(A + (size_t)(row0 + srow) * K + k0 + skk,           &As0[tid * 8]);
    load16_lds(A + (size_t)(row0 + 64 + srow) * K + k0 + skk,      &As0[2048 + tid * 8]);
    load16_lds(A + (size_t)(row0 + srow) * K + k0 + 32 + skk,      &As1[tid * 8]);
    load16_lds(A + (size_t)(row0 + 64 + srow) * K + k0 + 32 + skk, &As1[2048 + tid * 8]);
    load16_lds(B + (size_t)(col0 + srow) * K + k0 + skk,           &Bs0[tid * 8]);
    load16_lds(B + (size_t)(col0 + 64 + srow) * K + k0 + skk,      &Bs0[2048 + tid * 8]);
    load16_lds(B + (size_t)(col0 + srow) * K + k0 + 32 + skk,      &Bs1[tid * 8]);
    load16_lds(B + (size_t)(col0 + 64 + srow) * K + k0 + 32 + skk, &Bs1[2048 + tid * 8]);
    __syncthreads();
    {
      short8 af[4], bf[4];
#pragma unroll
      for (int i = 0; i < 4; ++i)
        af[i] = *(const short8*)&As0[(wrow + i * 16 + l16) * 32 + quad * 8];
#pragma unroll
      for (int j = 0; j < 4; ++j)
        bf[j] = *(const short8*)&Bs0[(wcol + j * 16 + l16) * 32 + quad * 8];
#pragma unroll
      for (int i = 0; i < 4; ++i)
#pragma unroll
        for (int j = 0; j < 4; ++j)
          acc[i][j] = __builtin_amdgcn_mfma_f32_16x16x32_bf16(af[i], bf[j], acc[i][j], 0, 0, 0);
    }
    {
      short8 af[4], bf[4];
#pragma unroll
      for (int i = 0; i < 4; ++i)
        af[i] = *(const short8*)&As1[(wrow + i * 16 + l16) * 32 + quad * 8];
#pragma unroll
      for (int j = 0; j < 4; ++j)
        bf[j] = *(const short8*)&Bs1[(wcol + j * 16 + l16) * 32 + quad * 8];
#pragma unroll
      for (int i = 0; i < 4; ++i)
#pragma unroll
        for (int j = 0; j < 4; ++j)
          acc[i][j] = __builtin_amdgcn_mfma_f32_16x16x32_bf16(af[i], bf[j], acc[i][j], 0, 0, 0);
    }
  }
#pragma unroll
  for (int i = 0; i < 4; ++i) {
#pragma unroll
    for (int j = 0; j < 4; ++j) {
      const int col = col0 + wcol + j * 16 + l16;
      const float bs = bias[col];
#pragma unroll
      for (int r = 0; r < 4; ++r) {
        const int row = row0 + wrow + i * 16 + quad * 4 + r;
        if (BF16OUT)
          ((__hip_bfloat16*)Cp)[(size_t)row * N + col] = __float2bfloat16(acc[i][j][r] + bs);
        else
          ((float*)Cp)[(size_t)row * N + col] = acc[i][j][r] + bs;
      }
    }
  }
}

// ---------------------------------------------------------------------------
// Spectral FFT body v3 (unchanged from R10): fused double radix-2 stages,
// bf16 xT in place. LDS: cx[2112] float2 = 16896 B.
// ---------------------------------------------------------------------------
#define PAD2(a) ((a) + ((a) >> 5))

__device__ __forceinline__ void spec_body(
    int sid, __hip_bfloat16* __restrict__ xw,
    const __hip_bfloat16* __restrict__ wrT, const __hip_bfloat16* __restrict__ wiT,
    float* smf) {
  float2* cx = (float2*)smf;
  const int tid = threadIdx.x;
  const int dpair = sid & 511;
  const int b = sid >> 9;
  const int d0 = dpair * 2, d1 = d0 + 1;
  __hip_bfloat16* col0 = xw + ((size_t)b * DD + d0) * SS;
  __hip_bfloat16* col1 = xw + ((size_t)b * DD + d1) * SS;

  // load two bf16 columns -> packed complex
  for (int s4 = tid * 4; s4 < SS; s4 += 1024) {
    const short4v a = *(const short4v*)(col0 + s4);
    const short4v c = *(const short4v*)(col1 + s4);
    const int p = PAD2(s4);
    cx[p + 0] = float2{bf2f(a[0]), bf2f(c[0])};
    cx[p + 1] = float2{bf2f(a[1]), bf2f(c[1])};
    cx[p + 2] = float2{bf2f(a[2]), bf2f(c[2])};
    cx[p + 3] = float2{bf2f(a[3]), bf2f(c[3])};
  }

  // ---- forward DIF: double stages s = 11,9,7,5,3 then single stage 1 ----
#pragma unroll
  for (int s = 11; s >= 3; s -= 2) {
    __syncthreads();
    const int h2 = 1 << (s - 2);
    const float ang = -6.283185307179586f / (float)(1 << s);
#pragma unroll 2
    for (int g = tid; g < 512; g += 256) {
      const int q = g & (h2 - 1);
      const int base = ((g >> (s - 2)) << s) + q;
      const int i0 = PAD2(base), i1 = PAD2(base + h2);
      const int i2 = PAD2(base + 2 * h2), i3 = PAD2(base + 3 * h2);
      float sn, cn;
      __sincosf(ang * (float)q, &sn, &cn);          // w1 = (cn, sn)
      const float2 A = cx[i0], B = cx[i1], C = cx[i2], D = cx[i3];
      const float2 Ap = {A.x + C.x, A.y + C.y};
      const float acx = A.x - C.x, acy = A.y - C.y;
      const float2 Cp = {acx * cn - acy * sn, acx * sn + acy * cn};
      const float2 Bp = {B.x + D.x, B.y + D.y};
      const float bdx = B.x - D.x, bdy = B.y - D.y;
      const float2 Dp = {bdx * sn + bdy * cn, bdy * sn - bdx * cn};  // *( -i*w1 )
      const float w3r = cn * cn - sn * sn, w3i = 2.f * cn * sn;     // w1^2
      cx[i0] = float2{Ap.x + Bp.x, Ap.y + Bp.y};
      const float abx = Ap.x - Bp.x, aby = Ap.y - Bp.y;
      cx[i1] = float2{abx * w3r - aby * w3i, abx * w3i + aby * w3r};
      cx[i2] = float2{Cp.x + Dp.x, Cp.y + Dp.y};
      const float cdx = Cp.x - Dp.x, cdy = Cp.y - Dp.y;
      cx[i3] = float2{cdx * w3r - cdy * w3i, cdx * w3i + cdy * w3r};
    }
  }
  __syncthreads();
  for (int t = tid; t < 1024; t += 256) {           // stage 1, twiddle = 1
    const int i = PAD2(2 * t), j = PAD2(2 * t + 1);
    const float2 a = cx[i], b = cx[j];
    cx[i] = float2{a.x + b.x, a.y + b.y};
    cx[j] = float2{a.x - b.x, a.y - b.y};
  }
  __syncthreads();

  // ---- packed Hermitian filter (bitrev positions), 1/S folded in ----
  const __hip_bfloat16* w0r = wrT + (size_t)d0 * 1025;
  const __hip_bfloat16* w0i = wiT + (size_t)d0 * 1025;
  const __hip_bfloat16* w1r = wrT + (size_t)d1 * 1025;
  const __hip_bfloat16* w1i = wiT + (size_t)d1 * 1025;
  const float sc = 1.0f / (float)SS;
  for (int k = tid; k < 1024; k += 256) {
    if (k == 0) {
      const float2 z0 = cx[0];
      cx[0] = float2{z0.x * __bfloat162float(w0r[0]) * sc,
                     z0.y * __bfloat162float(w1r[0]) * sc};
      const float2 zn = cx[1];
      cx[1] = float2{zn.x * __bfloat162float(w0r[1024]) * sc,
                     zn.y * __bfloat162float(w1r[1024]) * sc};
    } else {
      const int p1 = PAD2(__brev((unsigned)k) >> 21);
      const int p2 = PAD2(__brev((unsigned)(SS - k)) >> 21);
      const float2 A = cx[p1];
      const float2 Bv = cx[p2];
      const float z0r = 0.5f * (A.x + Bv.x), z0i = 0.5f * (A.y - Bv.y);
      const float z1r = 0.5f * (A.y + Bv.y), z1i = -0.5f * (A.x - Bv.x);
      const float a0 = __bfloat162float(w0r[k]) * sc, b0 = __bfloat162float(w0i[k]) * sc;
      const float a1 = __bfloat162float(w1r[k]) * sc, b1 = __bfloat162float(w1i[k]) * sc;
      const float y0r = z0r * a0 - z0i * b0, y0i = z0r * b0 + z0i * a0;
      const float y1r = z1r * a1 - z1i * b1, y1i = z1r * b1 + z1i * a1;
      cx[p1] = float2{y0r - y1i, y0i + y1r};
      cx[p2] = float2{y0r + y1i, y1r - y0i};
    }
  }

  // ---- inverse DIT: double stages s = 1,3,5,7,9 then single stage 11 ----
#pragma unroll
  for (int s = 1; s <= 9; s += 2) {
    __syncthreads();
    const int h = 1 << (s - 1);
    const float ang = -6.283185307179586f / (float)(1 << (s + 1));
#pragma unroll 2
    for (int g = tid; g < 512; g += 256) {
      const int q = g & (h - 1);
      const int base = ((g >> (s - 1)) << (s + 1)) + q;
      const int i0 = PAD2(base), i1 = PAD2(base + h);
      const int i2 = PAD2(base + 2 * h), i3 = PAD2(base + 3 * h);
      float sn, cn;
      __sincosf(ang * (float)q, &sn, &cn);   // wp = (cn, sn); conj used below
      const float wpr = cn, wpi = -sn;                       // conj(wp)
      const float wsr = cn * cn - sn * sn, wsi = -2.f * cn * sn;  // conj(wp)^2
      const float2 A = cx[i0], B = cx[i1], C = cx[i2], D = cx[i3];
      const float2 tB = {B.x * wsr - B.y * wsi, B.x * wsi + B.y * wsr};
      const float2 tD = {D.x * wsr - D.y * wsi, D.x * wsi + D.y * wsr};
      const float2 Ap = {A.x + tB.x, A.y + tB.y};
      const float2 Bp = {A.x - tB.x, A.y - tB.y};
      const float2 Cp = {C.x + tD.x, C.y + tD.y};
      const float2 Dp = {C.x - tD.x, C.y - tD.y};
      const float2 u = {Cp.x * wpr - Cp.y * wpi, Cp.x * wpi + Cp.y * wpr};
      const float2 v = {Dp.x * sn - Dp.y * cn, Dp.x * cn + Dp.y * sn}; // *(i*conj(wp))
      cx[i0] = float2{Ap.x + u.x, Ap.y + u.y};
      cx[i2] = float2{Ap.x - u.x, Ap.y - u.y};
      cx[i1] = float2{Bp.x + v.x, Bp.y + v.y};
      cx[i3] = float2{Bp.x - v.x, Bp.y - v.y};
    }
  }
  __syncthreads();
  for (int p = tid; p < 1024; p += 256) {    // stage 11: pairs (p, p+1024)
    float sn, cn;
    __sincosf(-6.283185307179586f * (float)p * (1.0f / 2048.0f), &sn, &cn);
    const int i = PAD2(p), j = PAD2(p + 1024);
    const float2 a = cx[i], b = cx[j];
    const float tr = b.x * cn + b.y * sn;    // b * conj(w)
    const float ti = b.y * cn - b.x * sn;
    cx[i] = float2{a.x + tr, a.y + ti};
    cx[j] = float2{a.x - tr, a.y - ti};
  }
  __syncthreads();

  // store bf16, in place
  for (int s4 = tid * 4; s4 < SS; s4 += 1024) {
    const int p = PAD2(s4);
    const float2 v0 = cx[p + 0], v1 = cx[p + 1], v2 = cx[p + 2], v3 = cx[p + 3];
    short4v a, c;
    a[0] = (short)__bfloat16_as_ushort(__float2bfloat16(v0.x));
    a[1] = (short)__bfloat16_as_ushort(__float2bfloat16(v1.x));
    a[2] = (short)__bfloat16_as_ushort(__float2bfloat16(v2.x));
    a[3] = (short)__bfloat16_as_ushort(__float2bfloat16(v3.x));
    c[0] = (short)__bfloat16_as_ushort(__float2bfloat16(v0.y));
    c[1] = (short)__bfloat16_as_ushort(__float2bfloat16(v1.y));
    c[2] = (short)__bfloat16_as_ushort(__float2bfloat16(v2.y));
    c[3] = (short)__bfloat16_as_ushort(__float2bfloat16(v3.y));
    *(short4v*)(col0 + s4) = a;
    *(short4v*)(col1 + s4) = c;
  }
}

// ---------------------------------------------------------------------------
// Fused launch 1: blocks [0,768) = QKV GEMM; [768,1280) = spectral FFT with
// 2 sequential FFT-pairs per block. 1280 blocks = exactly 5/CU x 256 CU at
// 32 KB dyn LDS -> single scheduling generation, no tail.
// ---------------------------------------------------------------------------
__global__ __launch_bounds__(256) void gemm1_spec(
    const __hip_bfloat16* __restrict__ x_bf, const __hip_bfloat16* __restrict__ w_in_bf,
    const float* __restrict__ in_b, __hip_bfloat16* __restrict__ qkv_bf,
    __hip_bfloat16* __restrict__ xT_bf, const __hip_bfloat16* __restrict__ wrT,
    const __hip_bfloat16* __restrict__ wiT) {
  extern __shared__ __align__(16) char smem[];
  if (blockIdx.x < 768) {
    const int id = blockIdx.x;
    const int col0 = (id % 24) * 128;
    const int row0 = (id / 24) * 128;
    gemm_tile128<true>(x_bf, w_in_bf, in_b, qkv_bf, 3 * DD, DD, row0, col0,
                       (__hip_bfloat16*)smem);
  } else {
    const int base = (blockIdx.x - 768) * 2;
    spec_body(base, xT_bf, wrT, wiT, (float*)smem);
    __syncthreads();
    spec_body(base + 1, xT_bf, wrT, wiT, (float*)smem);
  }
}

// ---------------------------------------------------------------------------
// Fused launch 2: blocks [0,256) = out-proj GEMM; [256,1280) = transpose-back
// xT_bf [b][d][s] -> x_wave_bf [b][s][d]. 1280 blocks = one generation.
// ---------------------------------------------------------------------------
__global__ __launch_bounds__(256) void gemm2_tback(
    const __hip_bfloat16* __restrict__ attn_bf, const __hip_bfloat16* __restrict__ w_out_bf,
    const float* __restrict__ out_b, __hip_bfloat16* __restrict__ attn_out_bf,
    const __hip_bfloat16* __restrict__ xT_bf, __hip_bfloat16* __restrict__ x_wave_bf) {
  extern __shared__ __align__(16) char smem[];
  if (blockIdx.x < 256) {
    const int id = blockIdx.x;
    const int col0 = (id % 8) * 128;
    const int row0 = (id / 8) * 128;
    gemm_tile128<true>(attn_bf, w_out_bf, out_b, attn_out_bf, DD, DD, row0, col0,
                       (__hip_bfloat16*)smem);
  } else {
    float (*tile)[65] = (float(*)[65])smem;
    const int id = blockIdx.x - 256;          // 0..1023
    const int bz = id >> 9;
    const int rem = id & 511;
    const int s0 = (rem >> 4) * 64;
    const int d0 = (rem & 15) * 64;
    const int tx = threadIdx.x & 63;
    const int ty = threadIdx.x >> 6;
    const __hip_bfloat16* src = xT_bf + (size_t)bz * DD * SS;
    __hip_bfloat16* dst = x_wave_bf + (size_t)bz * SS * DD;
#pragma unroll
    for (int i = 0; i < 16; ++i) {
      const int r = ty * 16 + i;
      tile[r][tx] = __bfloat162float(src[(size_t)(d0 + r) * SS + s0 + tx]);
    }
    __syncthreads();
#pragma unroll
    for (int i = 0; i < 16; ++i) {
      const int c = ty * 16 + i;
      dst[(size_t)(s0 + c) * DD + d0 + tx] = __float2bfloat16(tile[tx][c]);
    }
  }
}

// ---------------------------------------------------------------------------
// Flash-style MFMA sliding-window attention (unchanged).
// ---------------------------------------------------------------------------
__global__ __launch_bounds__(256, 2) void attn_mfma(
    const __hip_bfloat16* __restrict__ qkv, __hip_bfloat16* __restrict__ attn) {
  __shared__ __attribute__((aligned(16))) __hip_bfloat16 QsA[64 * 32];
  __shared__ __attribute__((aligned(16))) __hip_bfloat16 QsB[64 * 32];
  __shared__ __attribute__((aligned(16))) __hip_bfloat16 KsA[160 * 32];
  __shared__ __attribute__((aligned(16))) __hip_bfloat16 KsB[160 * 32];
  __shared__ __attribute__((aligned(16))) __hip_bfloat16 Vt[64 * 168];
  __shared__ __attribute__((aligned(16))) __hip_bfloat16 Ps[64 * 168];

  const int tid  = threadIdx.x;
  const int lane = tid & 63;
  const int w    = tid >> 6;
  const int quad = lane >> 4;
  const int l16  = lane & 15;
  const int q0   = blockIdx.x * 64;
  const int h    = blockIdx.y;
  const int b    = blockIdx.z;
  const int kbase = q0 - WINW;

  const int r_ = tid >> 2;
  const int c8 = (tid & 3) * 8;

  {
    const __hip_bfloat16* src = qkv + ((size_t)(b * SS + q0 + r_)) * (3 * DD) + h * DHH;
    load16_lds(src + c8,      &QsA[r_ * 32 + c8]);
    load16_lds(src + 32 + c8, &QsB[r_ * 32 + c8]);
  }

  short8 qf0, qf1;
  float m_run[4] = {-1e30f, -1e30f, -1e30f, -1e30f};
  float l_run[4] = {0.f, 0.f, 0.f, 0.f};
  floatx4 ob[4] = {};

  for (int c = 0; c < 2; ++c) {
    const int ck0 = kbase + c * 160;
    __syncthreads();
#pragma unroll
    for (int it = 0; it < 3; ++it) {
      const int r = it * 64 + r_;
      if (r < 160) {
        int key = ck0 + r; key = key < 0 ? 0 : (key > SS - 1 ? SS - 1 : key);
        const __hip_bfloat16* src = qkv + ((size_t)(b * SS + key)) * (3 * DD) + DD + h * DHH;
        load16_lds(src + c8,      &KsA[r * 32 + c8]);
        load16_lds(src + 32 + c8, &KsB[r * 32 + c8]);
      }
    }
    {
      const int k4 = (tid >> 3) * 4;
      const int d8 = (tid & 7) * 8;
#pragma unroll
      for (int it = 0; it < 2; ++it) {
        const int rr = it * 128 + k4;
        if (rr < 160) {
          short8 v[4];
#pragma unroll
          for (int u = 0; u < 4; ++u) {
            int key = ck0 + rr + u; key = key < 0 ? 0 : (key > SS - 1 ? SS - 1 : key);
            v[u] = *(const short8*)(qkv + ((size_t)(b * SS + key)) * (3 * DD) + 2 * DD + h * DHH + d8);
          }
#pragma unroll
          for (int j = 0; j < 8; ++j) {
            short4v pk; pk[0] = v[0][j]; pk[1] = v[1][j]; pk[2] = v[2][j]; pk[3] = v[3][j];
            *(short4v*)&Vt[(d8 + j) * 168 + rr] = pk;
          }
        }
      }
    }
    __syncthreads();

    if (c == 0) {
      qf0 = *(const short8*)&QsA[(w * 16 + l16) * 32 + quad * 8];
      qf1 = *(const short8*)&QsB[(w * 16 + l16) * 32 + quad * 8];
    }

    floatx4 sc[10];
#pragma unroll
    for (int kt = 0; kt < 10; ++kt) {
      const short8 bk0 = *(const short8*)&KsA[(kt * 16 + l16) * 32 + quad * 8];
      const short8 bk1 = *(const short8*)&KsB[(kt * 16 + l16) * 32 + quad * 8];
      floatx4 a = {};
      a = __builtin_amdgcn_mfma_f32_16x16x32_bf16(qf0, bk0, a, 0, 0, 0);
      a = __builtin_amdgcn_mfma_f32_16x16x32_bf16(qf1, bk1, a, 0, 0, 0);
      sc[kt] = a;
    }

    float cm[4] = {-1e30f, -1e30f, -1e30f, -1e30f};
#pragma unroll
    for (int kt = 0; kt < 10; ++kt) {
      const int key = ck0 + kt * 16 + l16;
#pragma unroll
      for (int r = 0; r < 4; ++r) {
        const int qq = q0 + w * 16 + quad * 4 + r;
        const int dqk = qq - key;
        const bool ok = (key >= 0) & (key < SS) & (dqk <= WINW) & (dqk >= -WINW);
        const float s = ok ? sc[kt][r] * 0.125f : -1e30f;
        sc[kt][r] = s;
        cm[r] = fmaxf(cm[r], s);
      }
    }
#pragma unroll
    for (int off = 1; off < 16; off <<= 1)
#pragma unroll
      for (int r = 0; r < 4; ++r) cm[r] = fmaxf(cm[r], __shfl_xor(cm[r], off, 64));

    float alpha[4], csum[4] = {0.f, 0.f, 0.f, 0.f};
#pragma unroll
    for (int r = 0; r < 4; ++r) {
      const float mn = fmaxf(m_run[r], cm[r]);
      alpha[r] = __expf(m_run[r] - mn);
      m_run[r] = mn;
    }

    __hip_bfloat16* Pw = &Ps[w * 16 * 168];
#pragma unroll
    for (int kt = 0; kt < 10; ++kt) {
#pragma unroll
      for (int r = 0; r < 4; ++r) {
        const float p = __expf(sc[kt][r] - m_run[r]);
        csum[r] += p;
        Pw[(quad * 4 + r) * 168 + kt * 16 + l16] = __float2bfloat16(p);
      }
    }
#pragma unroll
    for (int off = 1; off < 16; off <<= 1)
#pragma unroll
      for (int r = 0; r < 4; ++r) csum[r] += __shfl_xor(csum[r], off, 64);
#pragma unroll
    for (int r = 0; r < 4; ++r) l_run[r] = l_run[r] * alpha[r] + csum[r];
#pragma unroll
    for (int t = 0; t < 4; ++t)
#pragma unroll
      for (int r = 0; r < 4; ++r) ob[t][r] *= alpha[r];

#pragma unroll
    for (int kt = 0; kt < 5; ++kt) {
      const short8 pf = *(const short8*)&Pw[l16 * 168 + kt * 32 + quad * 8];
#pragma unroll
      for (int t = 0; t < 4; ++t) {
        const short8 vf = *(const short8*)&Vt[(t * 16 + l16) * 168 + kt * 32 + quad * 8];
        ob[t] = __builtin_amdgcn_mfma_f32_16x16x32_bf16(pf, vf, ob[t], 0, 0, 0);
      }
    }
  }

  float inv[4];
#pragma unroll
  for (int r = 0; r < 4; ++r) inv[r] = 1.f / l_run[r];
  const int qq0 = q0 + w * 16 + quad * 4;
#pragma unroll
  for (int t = 0; t < 4; ++t)
#pragma unroll
    for (int r = 0; r < 4; ++r)
      attn[((size_t)(b * SS + qq0 + r)) * DD + h * DHH + t * 16 + l16] =
          __float2bfloat16(ob[t][r] * inv[r]);
}

// ---------------------------------------------------------------------------
// Fused double LayerNorm: out = LN2( LN1(x + attn_out) + x_wave ).
// ---------------------------------------------------------------------------
__global__ __launch_bounds__(256) void ln_fused(
    const float* __restrict__ x, const __hip_bfloat16* __restrict__ attn_out,
    const float* __restrict__ g1, const float* __restrict__ b1,
    const __hip_bfloat16* __restrict__ xwave,
    const float* __restrict__ g2, const float* __restrict__ b2,
    float* __restrict__ out) {
  const int row = blockIdx.x;
  const int tid = threadIdx.x;
  const int lane = tid & 63;
  const int wave = tid >> 6;
  __shared__ float red[8];

  const float4 xv = *(const float4*)(x + (size_t)row * DD + tid * 4);
  const short4v av = *(const short4v*)(attn_out + (size_t)row * DD + tid * 4);
  float v[4] = {xv.x + bf2f(av[0]), xv.y + bf2f(av[1]),
                xv.z + bf2f(av[2]), xv.w + bf2f(av[3])};

  float s = v[0] + v[1] + v[2] + v[3];
  float s2 = v[0] * v[0] + v[1] * v[1] + v[2] * v[2] + v[3] * v[3];
#pragma unroll
  for (int off = 32; off; off >>= 1) {
    s += __shfl_xor(s, off, 64);
    s2 += __shfl_xor(s2, off, 64);
  }
  if (lane == 0) { red[wave] = s; red[4 + wave] = s2; }
  __syncthreads();
  s = red[0] + red[1] + red[2] + red[3];
  s2 = red[4] + red[5] + red[6] + red[7];
  float mu = s * (1.f / DD);
  float var = s2 * (1.f / DD) - mu * mu;
  float r = rsqrtf(var + 1e-5f);

  const float4 g1v = *(const float4*)(g1 + tid * 4);
  const float4 b1v = *(const float4*)(b1 + tid * 4);
  const short4v wv = *(const short4v*)(xwave + (size_t)row * DD + tid * 4);
  float a[4];
  a[0] = (v[0] - mu) * r * g1v.x + b1v.x + bf2f(wv[0]);
  a[1] = (v[1] - mu) * r * g1v.y + b1v.y + bf2f(wv[1]);
  a[2] = (v[2] - mu) * r * g1v.z + b1v.z + bf2f(wv[2]);
  a[3] = (v[3] - mu) * r * g1v.w + b1v.w + bf2f(wv[3]);

  s = a[0] + a[1] + a[2] + a[3];
  s2 = a[0] * a[0] + a[1] * a[1] + a[2] * a[2] + a[3] * a[3];
#pragma unroll
  for (int off = 32; off; off >>= 1) {
    s += __shfl_xor(s, off, 64);
    s2 += __shfl_xor(s2, off, 64);
  }
  __syncthreads();
  if (lane == 0) { red[wave] = s; red[4 + wave] = s2; }
  __syncthreads();
  s = red[0] + red[1] + red[2] + red[3];
  s2 = red[4] + red[5] + red[6] + red[7];
  mu = s * (1.f / DD);
  var = s2 * (1.f / DD) - mu * mu;
  r = rsqrtf(var + 1e-5f);

  const float4 g2v = *(const float4*)(g2 + tid * 4);
  const float4 b2v = *(const float4*)(b2 + tid * 4);
  float4 o;
  o.x = (a[0] - mu) * r * g2v.x + b2v.x;
  o.y = (a[1] - mu) * r * g2v.y + b2v.y;
  o.z = (a[2] - mu) * r * g2v.z + b2v.z;
  o.w = (a[3] - mu) * r * g2v.w + b2v.w;
  *(float4*)(out + (size_t)row * DD + tid * 4) = o;
}

// ---------------------------------------------------------------------------
extern "C" void kernel_launch(void* const* d_in, const int* in_sizes, int n_in,
                              void* d_out, int out_size, void* d_ws, size_t ws_size,
                              hipStream_t stream) {
  const float* x     = (const float*)d_in[0];
  const float* in_w  = (const float*)d_in[1];
  const float* in_b  = (const float*)d_in[2];
  const float* out_w = (const float*)d_in[3];
  const float* out_b = (const float*)d_in[4];
  const float* ln1_g = (const float*)d_in[5];
  const float* ln1_b = (const float*)d_in[6];
  const float* wr    = (const float*)d_in[7];
  const float* wi    = (const float*)d_in[8];
  const float* ln2_g = (const float*)d_in[9];
  const float* ln2_b = (const float*)d_in[10];
  float* out = (float*)d_out;

  char* ws = (char*)d_ws;
  __hip_bfloat16* xT_bf    = (__hip_bfloat16*)(ws);
  __hip_bfloat16* x_bf     = (__hip_bfloat16*)(ws + 16777216);
  __hip_bfloat16* attn_bf  = (__hip_bfloat16*)(ws + 16777216);
  __hip_bfloat16* w_in_bf  = (__hip_bfloat16*)(ws + 25165824);
  __hip_bfloat16* w_out_bf = (__hip_bfloat16*)(ws + 31457280);
  __hip_bfloat16* qkv_bf   = (__hip_bfloat16*)(ws + 33554432);
  __hip_bfloat16* attn_out_bf = (__hip_bfloat16*)(ws + 33554432);
  __hip_bfloat16* x_wave_bf   = (__hip_bfloat16*)(ws + 44040192);
  __hip_bfloat16* wrT      = (__hip_bfloat16*)(ws + 58720256);
  __hip_bfloat16* wiT      = (__hip_bfloat16*)(ws + 60819456);

  // 1. fused preprocessing (2080 blocks ~= one scheduling generation)
  prep_fused<<<2080, 256, 0, stream>>>(x, xT_bf, x_bf, in_w, out_w,
                                       w_in_bf, w_out_bf, wr, wi, wrT, wiT);

  // 2. fused: QKV GEMM (768) + spectral FFT (512 x 2 seq) = 1280 blocks
  gemm1_spec<<<1280, 256, 32768, stream>>>(x_bf, w_in_bf, in_b, qkv_bf,
                                           xT_bf, wrT, wiT);

  // 3. flash MFMA sliding-window attention
  attn_mfma<<<dim3(SS / 64, HH, BB), 256, 0, stream>>>(qkv_bf, attn_bf);

  // 4. fused: out-proj GEMM (256) + transpose-back (1024) = 1280 blocks
  gemm2_tback<<<1280, 256, 32768, stream>>>(attn_bf, w_out_bf, out_b,
                                            attn_out_bf, xT_bf, x_wave_bf);

  // 5. fused LN1+LN2 -> out
  ln_fused<<<MROWS, 256, 0, stream>>>(x, attn_out_bf, ln1_g, ln1_b,
                                      x_wave_bf, ln2_g, ln2_b, out);
}

// Round 12
// 208.645 us; speedup vs baseline: 1.0550x; 1.0550x over previous
//
#include <hip/hip_runtime.h>
#include <hip/hip_bf16.h>
#include <math.h>

// Problem constants (B,S,D,H,WIN) = (2,2048,1024,16,128), DH=64
#define BB    2
#define SS    2048
#define DD    1024
#define HH    16
#define DHH   64
#define WINW  128
#define MROWS (BB * SS)          // 4096

typedef __attribute__((ext_vector_type(8))) short short8;
typedef __attribute__((ext_vector_type(4))) short short4v;
typedef __attribute__((ext_vector_type(4))) float floatx4;

__device__ __forceinline__ float bf2f(short s) {
  union { unsigned u; float f; } t;
  t.u = ((unsigned)(unsigned short)s) << 16;
  return t.f;
}

// ---------------------------------------------------------------------------
__device__ inline void load16_lds(const __hip_bfloat16* g, __hip_bfloat16* l) {
  __builtin_amdgcn_global_load_lds(
      (const __attribute__((address_space(1))) uint32_t*)g,
      (__attribute__((address_space(3))) uint32_t*)l, 16, 0, 0);
}

// ---------------------------------------------------------------------------
// Fused preprocessing (one launch, 2592 blocks — R10 configuration):
//  [0,1024)    x fp32 -> xT_bf bf16 transposed + x_bf bf16 row-major
//  [1024,2048) weight casts fp32->bf16, 4096 elems/block
//  [2048,2592) wr/wi -> bf16 transposed [1024][1025]
// ---------------------------------------------------------------------------
__global__ __launch_bounds__(256) void prep_fused(
    const float* __restrict__ x, __hip_bfloat16* __restrict__ xT_bf,
    __hip_bfloat16* __restrict__ x_bf,
    const float* __restrict__ w_in, const float* __restrict__ w_out,
    __hip_bfloat16* __restrict__ w_in_bf, __hip_bfloat16* __restrict__ w_out_bf,
    const float* __restrict__ wr, const float* __restrict__ wi,
    __hip_bfloat16* __restrict__ wrT, __hip_bfloat16* __restrict__ wiT) {
  __shared__ float tile[64][65];
  const int id = blockIdx.x;
  const int tx = threadIdx.x & 63;
  const int ty = threadIdx.x >> 6;

  if (id < 1024) {
    const int bz = id >> 9;
    const int rem = id & 511;
    const int c0 = (rem & 15) * 64;   // D
    const int r0 = (rem >> 4) * 64;   // S
    const size_t base = (size_t)bz * SS * DD;
#pragma unroll
    for (int i = 0; i < 16; ++i) {
      const int r = ty * 16 + i;
      const float v = x[base + (size_t)(r0 + r) * DD + c0 + tx];
      tile[r][tx] = v;
      x_bf[base + (size_t)(r0 + r) * DD + c0 + tx] = __float2bfloat16(v);
    }
    __syncthreads();
#pragma unroll
    for (int i = 0; i < 16; ++i) {
      const int c = ty * 16 + i;
      xT_bf[base + (size_t)(c0 + c) * SS + r0 + tx] = __float2bfloat16(tile[tx][c]);
    }
  } else if (id < 2048) {
    const int blk = id - 1024;
    const float* src; __hip_bfloat16* dst; size_t off;
    if (blk < 768) { src = w_in; dst = w_in_bf; off = (size_t)blk * 4096; }
    else { src = w_out; dst = w_out_bf; off = (size_t)(blk - 768) * 4096; }
#pragma unroll
    for (int c = 0; c < 4; ++c) {
      const size_t j = off + c * 1024 + threadIdx.x * 4;
      const float4 v = *(const float4*)(src + j);
      dst[j + 0] = __float2bfloat16(v.x);
      dst[j + 1] = __float2bfloat16(v.y);
      dst[j + 2] = __float2bfloat16(v.z);
      dst[j + 3] = __float2bfloat16(v.w);
    }
  } else {
    const int id2 = id - 2048;               // 0..543
    const int half = id2 >= 272;
    const int rem = id2 - (half ? 272 : 0);
    const float* src = half ? wi : wr;
    __hip_bfloat16* dst = half ? wiT : wrT;
    const int R = 1025, C = DD;
    const int c0 = (rem & 15) * 64;
    const int r0 = (rem >> 4) * 64;
#pragma unroll
    for (int i = 0; i < 16; ++i) {
      const int r = ty * 16 + i;
      if (r0 + r < R) tile[r][tx] = src[(size_t)(r0 + r) * C + c0 + tx];
    }
    __syncthreads();
#pragma unroll
    for (int i = 0; i < 16; ++i) {
      const int c = ty * 16 + i;
      if (r0 + tx < R) dst[(size_t)(c0 + c) * R + r0 + tx] = __float2bfloat16(tile[tx][c]);
    }
  }
}

// ---------------------------------------------------------------------------
// bf16 MFMA GEMM tile body (BK=64). Kloop = K range to accumulate, ld = row
// stride of A and B (supports split-K: pass A/B offset + Kloop < ld).
// bias may be null (partials). sm: 32 KB.
// ---------------------------------------------------------------------------
__device__ __forceinline__ void gemm_tile128(
    const __hip_bfloat16* __restrict__ A, const __hip_bfloat16* __restrict__ B,
    const float* __restrict__ bias, __hip_bfloat16* __restrict__ Cp,
    int N, int Kloop, int ld, int row0, int col0, __hip_bfloat16* sm) {
  __hip_bfloat16* As0 = sm;
  __hip_bfloat16* As1 = sm + 4096;
  __hip_bfloat16* Bs0 = sm + 8192;
  __hip_bfloat16* Bs1 = sm + 12288;
  const int tid  = threadIdx.x;
  const int lane = tid & 63;
  const int wave = tid >> 6;
  const int wrow = (wave >> 1) * 64;
  const int wcol = (wave & 1) * 64;
  const int srow = tid >> 2;
  const int skk  = (tid & 3) * 8;
  const int quad = lane >> 4;
  const int l16  = lane & 15;
  floatx4 acc[4][4] = {};
  for (int k0 = 0; k0 < Kloop; k0 += 64) {
    __syncthreads();
    load16_lds(A + (size_t)(row0 + srow) * ld + k0 + skk,           &As0[tid * 8]);
    load16_lds(A + (size_t)(row0 + 64 + srow) * ld + k0 + skk,      &As0[2048 + tid * 8]);
    load16_lds(A + (size_t)(row0 + srow) * ld + k0 + 32 + skk,      &As1[tid * 8]);
    load16_lds(A + (size_t)(row0 + 64 + srow) * ld + k0 + 32 + skk, &As1[2048 + tid * 8]);
    load16_lds(B + (size_t)(col0 + srow) * ld + k0 + skk,           &Bs0[tid * 8]);
    load16_lds(B + (size_t)(col0 + 64 + srow) * ld + k0 + skk,      &Bs0[2048 + tid * 8]);
    load16_lds(B + (size_t)(col0 + srow) * ld + k0 + 32 + skk,      &Bs1[tid * 8]);
    load16_lds(B + (size_t)(col0 + 64 + srow) * ld + k0 + 32 + skk, &Bs1[2048 + tid * 8]);
    __syncthreads();
    {
      short8 af[4], bf[4];
#pragma unroll
      for (int i = 0; i < 4; ++i)
        af[i] = *(const short8*)&As0[(wrow + i * 16 + l16) * 32 + quad * 8];
#pragma unroll
      for (int j = 0; j < 4; ++j)
        bf[j] = *(const short8*)&Bs0[(wcol + j * 16 + l16) * 32 + quad * 8];
#pragma unroll
      for (int i = 0; i < 4; ++i)
#pragma unroll
        for (int j = 0; j < 4; ++j)
          acc[i][j] = __builtin_amdgcn_mfma_f32_16x16x32_bf16(af[i], bf[j], acc[i][j], 0, 0, 0);
    }
    {
      short8 af[4], bf[4];
#pragma unroll
      for (int i = 0; i < 4; ++i)
        af[i] = *(const short8*)&As1[(wrow + i * 16 + l16) * 32 + quad * 8];
#pragma unroll
      for (int j = 0; j < 4; ++j)
        bf[j] = *(const short8*)&Bs1[(wcol + j * 16 + l16) * 32 + quad * 8];
#pragma unroll
      for (int i = 0; i < 4; ++i)
#pragma unroll
        for (int j = 0; j < 4; ++j)
          acc[i][j] = __builtin_amdgcn_mfma_f32_16x16x32_bf16(af[i], bf[j], acc[i][j], 0, 0, 0);
    }
  }
#pragma unroll
  for (int i = 0; i < 4; ++i) {
#pragma unroll
    for (int j = 0; j < 4; ++j) {
      const int col = col0 + wcol + j * 16 + l16;
      const float bs = bias ? bias[col] : 0.f;
#pragma unroll
      for (int r = 0; r < 4; ++r) {
        const int row = row0 + wrow + i * 16 + quad * 4 + r;
        Cp[(size_t)row * N + col] = __float2bfloat16(acc[i][j][r] + bs);
      }
    }
  }
}

// ---------------------------------------------------------------------------
// Spectral FFT body v3 (unchanged): fused double radix-2 stages, bf16 xT in
// place. LDS: cx[2112] float2 = 16896 B.
// ---------------------------------------------------------------------------
#define PAD2(a) ((a) + ((a) >> 5))

__device__ __forceinline__ void spec_body(
    int sid, __hip_bfloat16* __restrict__ xw,
    const __hip_bfloat16* __restrict__ wrT, const __hip_bfloat16* __restrict__ wiT,
    float* smf) {
  float2* cx = (float2*)smf;
  const int tid = threadIdx.x;
  const int dpair = sid & 511;
  const int b = sid >> 9;
  const int d0 = dpair * 2, d1 = d0 + 1;
  __hip_bfloat16* col0 = xw + ((size_t)b * DD + d0) * SS;
  __hip_bfloat16* col1 = xw + ((size_t)b * DD + d1) * SS;

  for (int s4 = tid * 4; s4 < SS; s4 += 1024) {
    const short4v a = *(const short4v*)(col0 + s4);
    const short4v c = *(const short4v*)(col1 + s4);
    const int p = PAD2(s4);
    cx[p + 0] = float2{bf2f(a[0]), bf2f(c[0])};
    cx[p + 1] = float2{bf2f(a[1]), bf2f(c[1])};
    cx[p + 2] = float2{bf2f(a[2]), bf2f(c[2])};
    cx[p + 3] = float2{bf2f(a[3]), bf2f(c[3])};
  }

  // ---- forward DIF: double stages s = 11,9,7,5,3 then single stage 1 ----
#pragma unroll
  for (int s = 11; s >= 3; s -= 2) {
    __syncthreads();
    const int h2 = 1 << (s - 2);
    const float ang = -6.283185307179586f / (float)(1 << s);
#pragma unroll 2
    for (int g = tid; g < 512; g += 256) {
      const int q = g & (h2 - 1);
      const int base = ((g >> (s - 2)) << s) + q;
      const int i0 = PAD2(base), i1 = PAD2(base + h2);
      const int i2 = PAD2(base + 2 * h2), i3 = PAD2(base + 3 * h2);
      float sn, cn;
      __sincosf(ang * (float)q, &sn, &cn);          // w1 = (cn, sn)
      const float2 A = cx[i0], B = cx[i1], C = cx[i2], D = cx[i3];
      const float2 Ap = {A.x + C.x, A.y + C.y};
      const float acx = A.x - C.x, acy = A.y - C.y;
      const float2 Cp = {acx * cn - acy * sn, acx * sn + acy * cn};
      const float2 Bp = {B.x + D.x, B.y + D.y};
      const float bdx = B.x - D.x, bdy = B.y - D.y;
      const float2 Dp = {bdx * sn + bdy * cn, bdy * sn - bdx * cn};  // *( -i*w1 )
      const float w3r = cn * cn - sn * sn, w3i = 2.f * cn * sn;     // w1^2
      cx[i0] = float2{Ap.x + Bp.x, Ap.y + Bp.y};
      const float abx = Ap.x - Bp.x, aby = Ap.y - Bp.y;
      cx[i1] = float2{abx * w3r - aby * w3i, abx * w3i + aby * w3r};
      cx[i2] = float2{Cp.x + Dp.x, Cp.y + Dp.y};
      const float cdx = Cp.x - Dp.x, cdy = Cp.y - Dp.y;
      cx[i3] = float2{cdx * w3r - cdy * w3i, cdx * w3i + cdy * w3r};
    }
  }
  __syncthreads();
  for (int t = tid; t < 1024; t += 256) {           // stage 1, twiddle = 1
    const int i = PAD2(2 * t), j = PAD2(2 * t + 1);
    const float2 a = cx[i], b = cx[j];
    cx[i] = float2{a.x + b.x, a.y + b.y};
    cx[j] = float2{a.x - b.x, a.y - b.y};
  }
  __syncthreads();

  // ---- packed Hermitian filter (bitrev positions), 1/S folded in ----
  const __hip_bfloat16* w0r = wrT + (size_t)d0 * 1025;
  const __hip_bfloat16* w0i = wiT + (size_t)d0 * 1025;
  const __hip_bfloat16* w1r = wrT + (size_t)d1 * 1025;
  const __hip_bfloat16* w1i = wiT + (size_t)d1 * 1025;
  const float sc = 1.0f / (float)SS;
  for (int k = tid; k < 1024; k += 256) {
    if (k == 0) {
      const float2 z0 = cx[0];
      cx[0] = float2{z0.x * __bfloat162float(w0r[0]) * sc,
                     z0.y * __bfloat162float(w1r[0]) * sc};
      const float2 zn = cx[1];
      cx[1] = float2{zn.x * __bfloat162float(w0r[1024]) * sc,
                     zn.y * __bfloat162float(w1r[1024]) * sc};
    } else {
      const int p1 = PAD2(__brev((unsigned)k) >> 21);
      const int p2 = PAD2(__brev((unsigned)(SS - k)) >> 21);
      const float2 A = cx[p1];
      const float2 Bv = cx[p2];
      const float z0r = 0.5f * (A.x + Bv.x), z0i = 0.5f * (A.y - Bv.y);
      const float z1r = 0.5f * (A.y + Bv.y), z1i = -0.5f * (A.x - Bv.x);
      const float a0 = __bfloat162float(w0r[k]) * sc, b0 = __bfloat162float(w0i[k]) * sc;
      const float a1 = __bfloat162float(w1r[k]) * sc, b1 = __bfloat162float(w1i[k]) * sc;
      const float y0r = z0r * a0 - z0i * b0, y0i = z0r * b0 + z0i * a0;
      const float y1r = z1r * a1 - z1i * b1, y1i = z1r * b1 + z1i * a1;
      cx[p1] = float2{y0r - y1i, y0i + y1r};
      cx[p2] = float2{y0r + y1i, y1r - y0i};
    }
  }

  // ---- inverse DIT: double stages s = 1,3,5,7,9 then single stage 11 ----
#pragma unroll
  for (int s = 1; s <= 9; s += 2) {
    __syncthreads();
    const int h = 1 << (s - 1);
    const float ang = -6.283185307179586f / (float)(1 << (s + 1));
#pragma unroll 2
    for (int g = tid; g < 512; g += 256) {
      const int q = g & (h - 1);
      const int base = ((g >> (s - 1)) << (s + 1)) + q;
      const int i0 = PAD2(base), i1 = PAD2(base + h);
      const int i2 = PAD2(base + 2 * h), i3 = PAD2(base + 3 * h);
      float sn, cn;
      __sincosf(ang * (float)q, &sn, &cn);   // wp = (cn, sn); conj used below
      const float wpr = cn, wpi = -sn;                       // conj(wp)
      const float wsr = cn * cn - sn * sn, wsi = -2.f * cn * sn;  // conj(wp)^2
      const float2 A = cx[i0], B = cx[i1], C = cx[i2], D = cx[i3];
      const float2 tB = {B.x * wsr - B.y * wsi, B.x * wsi + B.y * wsr};
      const float2 tD = {D.x * wsr - D.y * wsi, D.x * wsi + D.y * wsr};
      const float2 Ap = {A.x + tB.x, A.y + tB.y};
      const float2 Bp = {A.x - tB.x, A.y - tB.y};
      const float2 Cp = {C.x + tD.x, C.y + tD.y};
      const float2 Dp = {C.x - tD.x, C.y - tD.y};
      const float2 u = {Cp.x * wpr - Cp.y * wpi, Cp.x * wpi + Cp.y * wpr};
      const float2 v = {Dp.x * sn - Dp.y * cn, Dp.x * cn + Dp.y * sn}; // *(i*conj(wp))
      cx[i0] = float2{Ap.x + u.x, Ap.y + u.y};
      cx[i2] = float2{Ap.x - u.x, Ap.y - u.y};
      cx[i1] = float2{Bp.x + v.x, Bp.y + v.y};
      cx[i3] = float2{Bp.x - v.x, Bp.y - v.y};
    }
  }
  __syncthreads();
  for (int p = tid; p < 1024; p += 256) {    // stage 11: pairs (p, p+1024)
    float sn, cn;
    __sincosf(-6.283185307179586f * (float)p * (1.0f / 2048.0f), &sn, &cn);
    const int i = PAD2(p), j = PAD2(p + 1024);
    const float2 a = cx[i], b = cx[j];
    const float tr = b.x * cn + b.y * sn;    // b * conj(w)
    const float ti = b.y * cn - b.x * sn;
    cx[i] = float2{a.x + tr, a.y + ti};
    cx[j] = float2{a.x - tr, a.y - ti};
  }
  __syncthreads();

  for (int s4 = tid * 4; s4 < SS; s4 += 1024) {
    const int p = PAD2(s4);
    const float2 v0 = cx[p + 0], v1 = cx[p + 1], v2 = cx[p + 2], v3 = cx[p + 3];
    short4v a, c;
    a[0] = (short)__bfloat16_as_ushort(__float2bfloat16(v0.x));
    a[1] = (short)__bfloat16_as_ushort(__float2bfloat16(v1.x));
    a[2] = (short)__bfloat16_as_ushort(__float2bfloat16(v2.x));
    a[3] = (short)__bfloat16_as_ushort(__float2bfloat16(v3.x));
    c[0] = (short)__bfloat16_as_ushort(__float2bfloat16(v0.y));
    c[1] = (short)__bfloat16_as_ushort(__float2bfloat16(v1.y));
    c[2] = (short)__bfloat16_as_ushort(__float2bfloat16(v2.y));
    c[3] = (short)__bfloat16_as_ushort(__float2bfloat16(v3.y));
    *(short4v*)(col0 + s4) = a;
    *(short4v*)(col1 + s4) = c;
  }
}

// ---------------------------------------------------------------------------
// Fused launch 1 (R10 config): blocks [0,768) = QKV GEMM; [768,1792) = FFT.
// Dynamic LDS 32768 B.
// ---------------------------------------------------------------------------
__global__ __launch_bounds__(256) void gemm1_spec(
    const __hip_bfloat16* __restrict__ x_bf, const __hip_bfloat16* __restrict__ w_in_bf,
    const float* __restrict__ in_b, __hip_bfloat16* __restrict__ qkv_bf,
    __hip_bfloat16* __restrict__ xT_bf, const __hip_bfloat16* __restrict__ wrT,
    const __hip_bfloat16* __restrict__ wiT) {
  extern __shared__ __align__(16) char smem[];
  if (blockIdx.x < 768) {
    const int id = blockIdx.x;
    const int col0 = (id % 24) * 128;
    const int row0 = (id / 24) * 128;
    gemm_tile128(x_bf, w_in_bf, in_b, qkv_bf, 3 * DD, DD, DD, row0, col0,
                 (__hip_bfloat16*)smem);
  } else {
    spec_body(blockIdx.x - 768, xT_bf, wrT, wiT, (float*)smem);
  }
}

// ---------------------------------------------------------------------------
// Fused launch 2: blocks [0,512) = out-proj GEMM split-K=2 (each block does
// half of K=1024 into its own bf16 partial buffer; sum + bias folded into
// ln_fused); blocks [512,1536) = transpose-back xT_bf -> x_wave_bf.
// Dynamic LDS 32768 B.
// ---------------------------------------------------------------------------
__global__ __launch_bounds__(256) void gemm2_tback(
    const __hip_bfloat16* __restrict__ attn_bf, const __hip_bfloat16* __restrict__ w_out_bf,
    __hip_bfloat16* __restrict__ p0, __hip_bfloat16* __restrict__ p1,
    const __hip_bfloat16* __restrict__ xT_bf, __hip_bfloat16* __restrict__ x_wave_bf) {
  extern __shared__ __align__(16) char smem[];
  if (blockIdx.x < 512) {
    const int t = blockIdx.x & 255;
    const int kh = blockIdx.x >> 8;           // 0 or 1
    const int col0 = (t % 8) * 128;
    const int row0 = (t / 8) * 128;
    gemm_tile128(attn_bf + kh * 512, w_out_bf + kh * 512, nullptr,
                 kh ? p1 : p0, DD, 512, DD, row0, col0,
                 (__hip_bfloat16*)smem);
  } else {
    float (*tile)[65] = (float(*)[65])smem;
    const int id = blockIdx.x - 512;          // 0..1023
    const int bz = id >> 9;
    const int rem = id & 511;
    const int s0 = (rem >> 4) * 64;
    const int d0 = (rem & 15) * 64;
    const int tx = threadIdx.x & 63;
    const int ty = threadIdx.x >> 6;
    const __hip_bfloat16* src = xT_bf + (size_t)bz * DD * SS;
    __hip_bfloat16* dst = x_wave_bf + (size_t)bz * SS * DD;
#pragma unroll
    for (int i = 0; i < 16; ++i) {
      const int r = ty * 16 + i;
      tile[r][tx] = __bfloat162float(src[(size_t)(d0 + r) * SS + s0 + tx]);
    }
    __syncthreads();
#pragma unroll
    for (int i = 0; i < 16; ++i) {
      const int c = ty * 16 + i;
      dst[(size_t)(s0 + c) * DD + d0 + tx] = __float2bfloat16(tile[tx][c]);
    }
  }
}

// ---------------------------------------------------------------------------
// Flash-style MFMA sliding-window attention (unchanged).
// ---------------------------------------------------------------------------
__global__ __launch_bounds__(256, 2) void attn_mfma(
    const __hip_bfloat16* __restrict__ qkv, __hip_bfloat16* __restrict__ attn) {
  __shared__ __attribute__((aligned(16))) __hip_bfloat16 QsA[64 * 32];
  __shared__ __attribute__((aligned(16))) __hip_bfloat16 QsB[64 * 32];
  __shared__ __attribute__((aligned(16))) __hip_bfloat16 KsA[160 * 32];
  __shared__ __attribute__((aligned(16))) __hip_bfloat16 KsB[160 * 32];
  __shared__ __attribute__((aligned(16))) __hip_bfloat16 Vt[64 * 168];
  __shared__ __attribute__((aligned(16))) __hip_bfloat16 Ps[64 * 168];

  const int tid  = threadIdx.x;
  const int lane = tid & 63;
  const int w    = tid >> 6;
  const int quad = lane >> 4;
  const int l16  = lane & 15;
  const int q0   = blockIdx.x * 64;
  const int h    = blockIdx.y;
  const int b    = blockIdx.z;
  const int kbase = q0 - WINW;

  const int r_ = tid >> 2;
  const int c8 = (tid & 3) * 8;

  {
    const __hip_bfloat16* src = qkv + ((size_t)(b * SS + q0 + r_)) * (3 * DD) + h * DHH;
    load16_lds(src + c8,      &QsA[r_ * 32 + c8]);
    load16_lds(src + 32 + c8, &QsB[r_ * 32 + c8]);
  }

  short8 qf0, qf1;
  float m_run[4] = {-1e30f, -1e30f, -1e30f, -1e30f};
  float l_run[4] = {0.f, 0.f, 0.f, 0.f};
  floatx4 ob[4] = {};

  for (int c = 0; c < 2; ++c) {
    const int ck0 = kbase + c * 160;
    __syncthreads();
#pragma unroll
    for (int it = 0; it < 3; ++it) {
      const int r = it * 64 + r_;
      if (r < 160) {
        int key = ck0 + r; key = key < 0 ? 0 : (key > SS - 1 ? SS - 1 : key);
        const __hip_bfloat16* src = qkv + ((size_t)(b * SS + key)) * (3 * DD) + DD + h * DHH;
        load16_lds(src + c8,      &KsA[r * 32 + c8]);
        load16_lds(src + 32 + c8, &KsB[r * 32 + c8]);
      }
    }
    {
      const int k4 = (tid >> 3) * 4;
      const int d8 = (tid & 7) * 8;
#pragma unroll
      for (int it = 0; it < 2; ++it) {
        const int rr = it * 128 + k4;
        if (rr < 160) {
          short8 v[4];
#pragma unroll
          for (int u = 0; u < 4; ++u) {
            int key = ck0 + rr + u; key = key < 0 ? 0 : (key > SS - 1 ? SS - 1 : key);
            v[u] = *(const short8*)(qkv + ((size_t)(b * SS + key)) * (3 * DD) + 2 * DD + h * DHH + d8);
          }
#pragma unroll
          for (int j = 0; j < 8; ++j) {
            short4v pk; pk[0] = v[0][j]; pk[1] = v[1][j]; pk[2] = v[2][j]; pk[3] = v[3][j];
            *(short4v*)&Vt[(d8 + j) * 168 + rr] = pk;
          }
        }
      }
    }
    __syncthreads();

    if (c == 0) {
      qf0 = *(const short8*)&QsA[(w * 16 + l16) * 32 + quad * 8];
      qf1 = *(const short8*)&QsB[(w * 16 + l16) * 32 + quad * 8];
    }

    floatx4 sc[10];
#pragma unroll
    for (int kt = 0; kt < 10; ++kt) {
      const short8 bk0 = *(const short8*)&KsA[(kt * 16 + l16) * 32 + quad * 8];
      const short8 bk1 = *(const short8*)&KsB[(kt * 16 + l16) * 32 + quad * 8];
      floatx4 a = {};
      a = __builtin_amdgcn_mfma_f32_16x16x32_bf16(qf0, bk0, a, 0, 0, 0);
      a = __builtin_amdgcn_mfma_f32_16x16x32_bf16(qf1, bk1, a, 0, 0, 0);
      sc[kt] = a;
    }

    float cm[4] = {-1e30f, -1e30f, -1e30f, -1e30f};
#pragma unroll
    for (int kt = 0; kt < 10; ++kt) {
      const int key = ck0 + kt * 16 + l16;
#pragma unroll
      for (int r = 0; r < 4; ++r) {
        const int qq = q0 + w * 16 + quad * 4 + r;
        const int dqk = qq - key;
        const bool ok = (key >= 0) & (key < SS) & (dqk <= WINW) & (dqk >= -WINW);
        const float s = ok ? sc[kt][r] * 0.125f : -1e30f;
        sc[kt][r] = s;
        cm[r] = fmaxf(cm[r], s);
      }
    }
#pragma unroll
    for (int off = 1; off < 16; off <<= 1)
#pragma unroll
      for (int r = 0; r < 4; ++r) cm[r] = fmaxf(cm[r], __shfl_xor(cm[r], off, 64));

    float alpha[4], csum[4] = {0.f, 0.f, 0.f, 0.f};
#pragma unroll
    for (int r = 0; r < 4; ++r) {
      const float mn = fmaxf(m_run[r], cm[r]);
      alpha[r] = __expf(m_run[r] - mn);
      m_run[r] = mn;
    }

    __hip_bfloat16* Pw = &Ps[w * 16 * 168];
#pragma unroll
    for (int kt = 0; kt < 10; ++kt) {
#pragma unroll
      for (int r = 0; r < 4; ++r) {
        const float p = __expf(sc[kt][r] - m_run[r]);
        csum[r] += p;
        Pw[(quad * 4 + r) * 168 + kt * 16 + l16] = __float2bfloat16(p);
      }
    }
#pragma unroll
    for (int off = 1; off < 16; off <<= 1)
#pragma unroll
      for (int r = 0; r < 4; ++r) csum[r] += __shfl_xor(csum[r], off, 64);
#pragma unroll
    for (int r = 0; r < 4; ++r) l_run[r] = l_run[r] * alpha[r] + csum[r];
#pragma unroll
    for (int t = 0; t < 4; ++t)
#pragma unroll
      for (int r = 0; r < 4; ++r) ob[t][r] *= alpha[r];

#pragma unroll
    for (int kt = 0; kt < 5; ++kt) {
      const short8 pf = *(const short8*)&Pw[l16 * 168 + kt * 32 + quad * 8];
#pragma unroll
      for (int t = 0; t < 4; ++t) {
        const short8 vf = *(const short8*)&Vt[(t * 16 + l16) * 168 + kt * 32 + quad * 8];
        ob[t] = __builtin_amdgcn_mfma_f32_16x16x32_bf16(pf, vf, ob[t], 0, 0, 0);
      }
    }
  }

  float inv[4];
#pragma unroll
  for (int r = 0; r < 4; ++r) inv[r] = 1.f / l_run[r];
  const int qq0 = q0 + w * 16 + quad * 4;
#pragma unroll
  for (int t = 0; t < 4; ++t)
#pragma unroll
    for (int r = 0; r < 4; ++r)
      attn[((size_t)(b * SS + qq0 + r)) * DD + h * DHH + t * 16 + l16] =
          __float2bfloat16(ob[t][r] * inv[r]);
}

// ---------------------------------------------------------------------------
// Fused double LayerNorm with split-K reduction:
// out = LN2( LN1(x + p0 + p1 + out_b) + x_wave ).  x read as bf16.
// ---------------------------------------------------------------------------
__global__ __launch_bounds__(256) void ln_fused(
    const __hip_bfloat16* __restrict__ x_bf,
    const __hip_bfloat16* __restrict__ p0, const __hip_bfloat16* __restrict__ p1,
    const float* __restrict__ out_b,
    const float* __restrict__ g1, const float* __restrict__ b1,
    const __hip_bfloat16* __restrict__ xwave,
    const float* __restrict__ g2, const float* __restrict__ b2,
    float* __restrict__ out) {
  const int row = blockIdx.x;
  const int tid = threadIdx.x;
  const int lane = tid & 63;
  const int wave = tid >> 6;
  __shared__ float red[8];

  const short4v xv = *(const short4v*)(x_bf + (size_t)row * DD + tid * 4);
  const short4v a0 = *(const short4v*)(p0 + (size_t)row * DD + tid * 4);
  const short4v a1 = *(const short4v*)(p1 + (size_t)row * DD + tid * 4);
  const float4 obv = *(const float4*)(out_b + tid * 4);
  float v[4];
  v[0] = bf2f(xv[0]) + bf2f(a0[0]) + bf2f(a1[0]) + obv.x;
  v[1] = bf2f(xv[1]) + bf2f(a0[1]) + bf2f(a1[1]) + obv.y;
  v[2] = bf2f(xv[2]) + bf2f(a0[2]) + bf2f(a1[2]) + obv.z;
  v[3] = bf2f(xv[3]) + bf2f(a0[3]) + bf2f(a1[3]) + obv.w;

  float s = v[0] + v[1] + v[2] + v[3];
  float s2 = v[0] * v[0] + v[1] * v[1] + v[2] * v[2] + v[3] * v[3];
#pragma unroll
  for (int off = 32; off; off >>= 1) {
    s += __shfl_xor(s, off, 64);
    s2 += __shfl_xor(s2, off, 64);
  }
  if (lane == 0) { red[wave] = s; red[4 + wave] = s2; }
  __syncthreads();
  s = red[0] + red[1] + red[2] + red[3];
  s2 = red[4] + red[5] + red[6] + red[7];
  float mu = s * (1.f / DD);
  float var = s2 * (1.f / DD) - mu * mu;
  float r = rsqrtf(var + 1e-5f);

  const float4 g1v = *(const float4*)(g1 + tid * 4);
  const float4 b1v = *(const float4*)(b1 + tid * 4);
  const short4v wv = *(const short4v*)(xwave + (size_t)row * DD + tid * 4);
  float a[4];
  a[0] = (v[0] - mu) * r * g1v.x + b1v.x + bf2f(wv[0]);
  a[1] = (v[1] - mu) * r * g1v.y + b1v.y + bf2f(wv[1]);
  a[2] = (v[2] - mu) * r * g1v.z + b1v.z + bf2f(wv[2]);
  a[3] = (v[3] - mu) * r * g1v.w + b1v.w + bf2f(wv[3]);

  s = a[0] + a[1] + a[2] + a[3];
  s2 = a[0] * a[0] + a[1] * a[1] + a[2] * a[2] + a[3] * a[3];
#pragma unroll
  for (int off = 32; off; off >>= 1) {
    s += __shfl_xor(s, off, 64);
    s2 += __shfl_xor(s2, off, 64);
  }
  __syncthreads();
  if (lane == 0) { red[wave] = s; red[4 + wave] = s2; }
  __syncthreads();
  s = red[0] + red[1] + red[2] + red[3];
  s2 = red[4] + red[5] + red[6] + red[7];
  mu = s * (1.f / DD);
  var = s2 * (1.f / DD) - mu * mu;
  r = rsqrtf(var + 1e-5f);

  const float4 g2v = *(const float4*)(g2 + tid * 4);
  const float4 b2v = *(const float4*)(b2 + tid * 4);
  float4 o;
  o.x = (a[0] - mu) * r * g2v.x + b2v.x;
  o.y = (a[1] - mu) * r * g2v.y + b2v.y;
  o.z = (a[2] - mu) * r * g2v.z + b2v.z;
  o.w = (a[3] - mu) * r * g2v.w + b2v.w;
  *(float4*)(out + (size_t)row * DD + tid * 4) = o;
}

// ---------------------------------------------------------------------------
extern "C" void kernel_launch(void* const* d_in, const int* in_sizes, int n_in,
                              void* d_out, int out_size, void* d_ws, size_t ws_size,
                              hipStream_t stream) {
  const float* x     = (const float*)d_in[0];
  const float* in_w  = (const float*)d_in[1];
  const float* in_b  = (const float*)d_in[2];
  const float* out_w = (const float*)d_in[3];
  const float* out_b = (const float*)d_in[4];
  const float* ln1_g = (const float*)d_in[5];
  const float* ln1_b = (const float*)d_in[6];
  const float* wr    = (const float*)d_in[7];
  const float* wi    = (const float*)d_in[8];
  const float* ln2_g = (const float*)d_in[9];
  const float* ln2_b = (const float*)d_in[10];
  float* out = (float*)d_out;

  char* ws = (char*)d_ws;
  // Workspace (<= 64 MB):
  //  [0,8.4)     xT_bf (FFT in place, read by tback)
  //  [8.4,16.8)  x_bf (live until ln)
  //  [16.8,25.2) attn_bf
  //  [25.2,31.5) w_in_bf ; [31.5,33.5) w_out_bf
  //  [33.5,58.7) qkv_bf (dead after attn) -> p0 [33.5,41.9) + p1 [41.9,50.3)
  //              + x_wave_bf [50.3,58.7)
  //  [58.7,60.8) wrT ; [60.8,62.9) wiT
  __hip_bfloat16* xT_bf    = (__hip_bfloat16*)(ws);
  __hip_bfloat16* x_bf     = (__hip_bfloat16*)(ws + 8388608);
  __hip_bfloat16* attn_bf  = (__hip_bfloat16*)(ws + 16777216);
  __hip_bfloat16* w_in_bf  = (__hip_bfloat16*)(ws + 25165824);
  __hip_bfloat16* w_out_bf = (__hip_bfloat16*)(ws + 31457280);
  __hip_bfloat16* qkv_bf   = (__hip_bfloat16*)(ws + 33554432);
  __hip_bfloat16* p0       = (__hip_bfloat16*)(ws + 33554432);
  __hip_bfloat16* p1       = (__hip_bfloat16*)(ws + 41943040);
  __hip_bfloat16* x_wave_bf= (__hip_bfloat16*)(ws + 50331648);
  __hip_bfloat16* wrT      = (__hip_bfloat16*)(ws + 58720256);
  __hip_bfloat16* wiT      = (__hip_bfloat16*)(ws + 60819456);

  // 1. fused preprocessing (R10 config)
  prep_fused<<<2592, 256, 0, stream>>>(x, xT_bf, x_bf, in_w, out_w,
                                       w_in_bf, w_out_bf, wr, wi, wrT, wiT);

  // 2. fused: QKV GEMM (768 blocks) + spectral FFT (1024 blocks)
  gemm1_spec<<<1792, 256, 32768, stream>>>(x_bf, w_in_bf, in_b, qkv_bf,
                                           xT_bf, wrT, wiT);

  // 3. flash MFMA sliding-window attention
  attn_mfma<<<dim3(SS / 64, HH, BB), 256, 0, stream>>>(qkv_bf, attn_bf);

  // 4. fused: out-proj GEMM split-K=2 (512 blocks) + transpose-back (1024)
  gemm2_tback<<<1536, 256, 32768, stream>>>(attn_bf, w_out_bf, p0, p1,
                                            xT_bf, x_wave_bf);

  // 5. fused LN1+LN2 with split-K reduction + out-proj bias -> out
  ln_fused<<<MROWS, 256, 0, stream>>>(x_bf, p0, p1, out_b, ln1_g, ln1_b,
                                      x_wave_bf, ln2_g, ln2_b, out);
}